// Round 4
// baseline (216.311 us; speedup 1.0000x reference)
//
#include <hip/hip_runtime.h>
#include <math.h>

#define T_STEPS 730
#define NB      1000
#define LENF    15
#define NEARZ   1e-5f
#define SGW     8000           // 1000 basins x 8 members

// ===========================================================================
// 8-lane butterfly reduction (groups of 8 consecutive lanes = one basin).
// old=0 + bound_ctrl=1 -> GCNDPPCombine fuses mov_dpp+add into v_add_f32_dpp.
// ===========================================================================
template <int CTRL>
__device__ __forceinline__ float dpp_mov(float x) {
    int xi = __builtin_bit_cast(int, x);
    int r  = __builtin_amdgcn_update_dpp(0, xi, CTRL, 0xF, 0xF, true);
    return __builtin_bit_cast(float, r);
}
__device__ __forceinline__ float sum8(float v) {
    v += dpp_mov<0xB1>(v);    // xor 1 (quad swap-pairs)
    v += dpp_mov<0x4E>(v);    // xor 2 (quad swap-halves)
    v += dpp_mov<0x141>(v);   // row half-mirror (completes 8-group)
    return v;
}

// ===========================================================================
// FUSED PASS: serial S/G recurrence + in-wave member reduction.
// R13: the split design round-tripped a 46.7MB (S,G) plane (write + 1.28x
// read) + re-did exp2 to reconstruct Y -> ~20us finalize floor.  The scan
// pass has spare issue slots (94cy/step budget, ~34cy used), so the 5 sum8
// reductions (15 fused DPP-adds) ride along ~free-ish and the intermediate
// shrinks to a 5.8MB (qs,qg) plane + direct ch3..5 writes.
//   AET mean = (sum Y - sum Sn)/8  -> no exp2 reconstruction, no halo seams.
// Per step: 16 physics + 15 dpp + ~10 select/addr + 2 stores, all exact.
// Forcing staged in LDS (R12): steady-state loop has no global loads, so no
// vmcnt waits couple to the store queue.
// ===========================================================================
#define STEPC(CURV)                                                           \
  {                                                                           \
    float pcp = (CURV).x, pet = (CURV).y;                                     \
    float W     = pcp + S;                                                    \
    float term  = fmaf(W, inv2a, pb2a);                                       \
    float disc  = fmaf(term, term, -(W * boa));                               \
    float r     = __builtin_amdgcn_sqrtf(fmaxf(disc, NEARZ));                 \
    float Y     = term - r;                                                   \
    float e     = __builtin_amdgcn_exp2f(pet * nbl);                          \
    float Sn    = Y * e;                                                      \
    float avail = W - Y;                                                      \
    float Gn    = fmaf(pc, avail, G) * i1d;                                   \
    float Qs    = omc * avail;                                                \
    float Qg    = pd * Gn;                                                    \
    S = Sn; G = Gn;                                                           \
    float qs_s = sum8(Qs);                                                    \
    float qg_s = sum8(Qg);                                                    \
    float y_s  = sum8(Y);                                                     \
    float s_s  = sum8(Sn);                                                    \
    float g_s  = sum8(Gn);                                                    \
    if (m == 3) *qp = make_float2(qs_s, qg_s);                                \
    float ov = (m == 0) ? (y_s - s_s) : ((m == 1) ? s_s : g_s);               \
    if (m < 3) *optr = ov * 0.125f;                                           \
    qp += NB; optr += NB * 6;                                                 \
  }

// LDS prefetch: rows up to 735 valid (duplicates of 729) -> no clamp.
#define PREFETCH(BUF, CI)                                                      \
  _Pragma("unroll")                                                            \
  for (int j = 0; j < 8; ++j) {                                                \
      BUF[j] = xs[((CI) * 8 + j) * 8 + bl];                                    \
  }                                                                            \
  __builtin_amdgcn_sched_barrier(0);

__global__ __launch_bounds__(64, 1) void scan_fused(const float* __restrict__ x,
                                                    const float* __restrict__ raw,
                                                    float2* __restrict__ qsg,
                                                    float* __restrict__ out) {
    __shared__ float4 xs4[2944];               // 736 rows x 8 basins x float2
    const float2* xs = (const float2*)xs4;

    const int L   = threadIdx.x;
    const int gid = blockIdx.x * 64 + L;       // 0..7999 (grid=125)
    const int b   = gid >> 3;
    const int m   = gid & 7;
    const int bl  = L >> 3;                    // basin-local 0..7

    // ---- one-time cooperative x -> LDS stage ------------------------------
    {
        float4 tmp[46];
#pragma unroll
        for (int ch = 0; ch < 46; ++ch) {
            int idx = ch * 64 + L;             // 0..2943
            int row = idx >> 2;                // t row 0..735
            row = row < T_STEPS ? row : (T_STEPS - 1);
            tmp[ch] = *(const float4*)((const char*)x + (size_t)row * (NB * 8)
                                       + (size_t)(blockIdx.x * 64)
                                       + (size_t)(idx & 3) * 16);
        }
#pragma unroll
        for (int ch = 0; ch < 46; ++ch) xs4[ch * 64 + L] = tmp[ch];
    }
    __syncthreads();

    // raw layout (B,34) = [a(8), b(8), c(8), d(8), ra, rb]
    const float* rp = raw + b * 34;
    float pa = rp[0 * 8 + m] * 0.9f + 0.1f;
    float pb = rp[1 * 8 + m] * 450.0f + 50.0f;
    float pc = rp[2 * 8 + m];
    float pd = rp[3 * 8 + m] * 0.89f + 0.01f;

    float inv2a = 1.0f / (2.0f * pa);
    float pb2a  = pb * inv2a;
    float boa   = pb / pa;
    float nbl   = -1.4426950408889634f / pb;   // exp(-pet/b)=exp2(pet*this)
    float i1d   = 1.0f / (1.0f + pd);
    float omc   = 1.0f - pc;

    float S = 50.0f, G = 10.0f;
    float2* qp   = qsg + b;                          // lane m==3 writes
    float*  optr = out + (size_t)b * 6 + 3 + (m < 3 ? m : 0);  // lanes m<3

    float2 A[8], Bb[8], Cc[8];
    PREFETCH(A, 0)
    PREFETCH(Bb, 1)

    // 15 groups x 48 steps (6 chunks of 8) = 720 steps, + 10-step tail.
    for (int g = 0; g < 15; ++g) {
        const int c0 = 6 * g;
        PREFETCH(Cc, c0 + 2)
#pragma unroll
        for (int j = 0; j < 8; ++j) STEPC(A[j])
        PREFETCH(A, c0 + 3)
#pragma unroll
        for (int j = 0; j < 8; ++j) STEPC(Bb[j])
        PREFETCH(Bb, c0 + 4)
#pragma unroll
        for (int j = 0; j < 8; ++j) STEPC(Cc[j])
        PREFETCH(Cc, c0 + 5)
#pragma unroll
        for (int j = 0; j < 8; ++j) STEPC(A[j])
        PREFETCH(A, c0 + 6)
#pragma unroll
        for (int j = 0; j < 8; ++j) STEPC(Bb[j])
        PREFETCH(Bb, c0 + 7)
#pragma unroll
        for (int j = 0; j < 8; ++j) STEPC(Cc[j])
    }
    // tail: A = rows 720..727, Bb[0]=728, Bb[1]=729
#pragma unroll
    for (int j = 0; j < 8; ++j) STEPC(A[j])
    STEPC(Bb[0])
    STEPC(Bb[1])
}

// ===========================================================================
// UH weights, 0.125 ensemble mean folded (gammaln cancels under norm).
// ===========================================================================
__global__ __launch_bounds__(256) void uh_k(const float* __restrict__ raw,
                                            float* __restrict__ uh) {
    int b = blockIdx.x * 256 + threadIdx.x;
    if (b >= NB) return;
    float ra = raw[b * 34 + 32] * 2.9f;
    float rb = raw[b * 34 + 33] * 6.5f;
    float aa = fmaxf(ra, 0.0f) + 0.1f;
    float th = fmaxf(rb, 0.0f) + 0.5f;
    float inv_th = 1.0f / th;
    float am1 = aa - 1.0f;
    float w[LENF];
    float s = 0.0f;
#pragma unroll
    for (int k = 0; k < LENF; ++k) {
        float t = (float)k + 0.5f;
        w[k] = __expf(am1 * __logf(t) - t * inv_th);
        s += w[k];
    }
    float invs = 0.125f / s;       // UH normalization x ensemble mean
#pragma unroll
    for (int k = 0; k < LENF; ++k) uh[k * NB + b] = w[k] * invs;
}

// ===========================================================================
// 15-tap causal conv on the compact (qs,qg) plane -> out ch0..2.
// thread=basin (coalesced float2 row reads; plane is L2-resident 5.8MB).
// ===========================================================================
__global__ __launch_bounds__(256) void conv2(const float2* __restrict__ qsg,
                                             const float* __restrict__ uh,
                                             float* __restrict__ out) {
    int b = blockIdx.x * 256 + threadIdx.x;
    int t = blockIdx.y;
    if (b >= NB) return;
    float ys = 0.0f, yg = 0.0f;
    int kmax = t < (LENF - 1) ? t : (LENF - 1);
    for (int k = 0; k <= kmax; ++k) {
        float w  = uh[k * NB + b];
        float2 q = qsg[(size_t)(t - k) * NB + b];
        ys = fmaf(q.x, w, ys);
        yg = fmaf(q.y, w, yg);
    }
    float* o = out + ((size_t)t * NB + b) * 6;
    *(float2*)o = make_float2(ys + yg, ys);    // 8B-aligned (24|addr)
    o[2] = yg;
}

// ===========================================================================
// FALLBACK (ws too small): R8's proven path.
// ===========================================================================
#define STEPF(CURV)                                                            \
  {                                                                            \
    float pcp = (CURV).x, pet = (CURV).y;                                      \
    float W     = pcp + S;                                                     \
    float term  = fmaf(W, inv2a, pb2a);                                        \
    float disc  = fmaf(term, term, -(W * boa));                                \
    float r     = __builtin_amdgcn_sqrtf(fmaxf(disc, NEARZ));                  \
    float Y     = term - r;                                                    \
    float e     = __builtin_amdgcn_exp2f(pet * ninvbl2);                       \
    float Sn    = Y * e;                                                       \
    float AET   = Y - Sn;                                                      \
    float avail = W - Y;                                                       \
    float Qs    = omc * avail;                                                 \
    float Gn    = fmaf(pc, avail, G) * inv1pd;                                 \
    float Qg    = pd * Gn;                                                     \
    S = Sn; G = Gn;                                                            \
    float qs_s = sum8(Qs);                                                     \
    float qg_s = sum8(Qg);                                                     \
    float ae_s = sum8(AET);                                                    \
    float s_s  = sum8(Sn);                                                     \
    float g_s  = sum8(Gn);                                                     \
    float v = qs_s;                                                            \
    v = (m == 1) ? qg_s : v;                                                   \
    v = (m == 2) ? ae_s : v;                                                   \
    v = (m == 3) ? s_s  : v;                                                   \
    v = (m >= 4) ? g_s  : v;                                                   \
    *optr = v * 0.125f;                                                        \
    optr += incr;                                                              \
  }

__global__ __launch_bounds__(64, 1) void scan_fb(const float* __restrict__ x,
                                                 const float* __restrict__ raw,
                                                 float* __restrict__ out,
                                                 float* __restrict__ qs_ws,
                                                 float* __restrict__ qg_ws,
                                                 float* __restrict__ dummy) {
    const int L  = threadIdx.x;
    const int lb = L >> 3;
    const int m  = L & 7;
    const int b  = blockIdx.x * 8 + lb;

    const float* rp = raw + b * 34;
    float pa = rp[0 * 8 + m] * 0.9f + 0.1f;
    float pb = rp[1 * 8 + m] * 450.0f + 50.0f;
    float pc = rp[2 * 8 + m];
    float pd = rp[3 * 8 + m] * 0.89f + 0.01f;
    float inv2a   = 1.0f / (2.0f * pa);
    float pb2a    = pb * inv2a;
    float boa     = pb / pa;
    float ninvbl2 = -1.4426950408889634f / pb;
    float omc     = 1.0f - pc;
    float inv1pd  = 1.0f / (1.0f + pd);

    float* optr;
    long long incr;
    if      (m == 0) { optr = qs_ws + b;                      incr = NB;     }
    else if (m == 1) { optr = qg_ws + b;                      incr = NB;     }
    else if (m <= 4) { optr = out + (long long)b * 6 + m + 1; incr = NB * 6; }
    else             { optr = dummy + (blockIdx.x * 64 + L);  incr = 0;      }

    float S = 50.0f, G = 10.0f;
    const float2* __restrict__ xf = (const float2*)x;

    float2 A[10], B[10], C[10];
#pragma unroll
    for (int j = 0; j < 10; ++j) A[j] = xf[j * NB + b];
#pragma unroll
    for (int j = 0; j < 10; ++j) B[j] = xf[(10 + j) * NB + b];

    for (int cg = 0; cg < 24; ++cg) {
        const int c0 = 3 * cg;
#pragma unroll
        for (int j = 0; j < 10; ++j) C[j] = xf[((c0 + 2) * 10 + j) * NB + b];
        __builtin_amdgcn_sched_barrier(0);
#pragma unroll
        for (int j = 0; j < 10; ++j) STEPF(A[j]);
#pragma unroll
        for (int j = 0; j < 10; ++j) A[j] = xf[((c0 + 3) * 10 + j) * NB + b];
        __builtin_amdgcn_sched_barrier(0);
#pragma unroll
        for (int j = 0; j < 10; ++j) STEPF(B[j]);
#pragma unroll
        for (int j = 0; j < 10; ++j) {
            int t = (c0 + 4) * 10 + j;
            t = t < T_STEPS ? t : (T_STEPS - 1);
            B[j] = xf[t * NB + b];
        }
        __builtin_amdgcn_sched_barrier(0);
#pragma unroll
        for (int j = 0; j < 10; ++j) STEPF(C[j]);
    }
#pragma unroll
    for (int j = 0; j < 10; ++j) STEPF(A[j]);
}

__global__ __launch_bounds__(256) void uh_fb(const float* __restrict__ raw,
                                             float* __restrict__ uh) {
    int b = blockIdx.x * 256 + threadIdx.x;
    if (b >= NB) return;
    float ra = raw[b * 34 + 32] * 2.9f;
    float rb = raw[b * 34 + 33] * 6.5f;
    float aa = fmaxf(ra, 0.0f) + 0.1f;
    float th = fmaxf(rb, 0.0f) + 0.5f;
    float inv_th = 1.0f / th;
    float am1 = aa - 1.0f;
    float w[LENF];
    float s = 0.0f;
#pragma unroll
    for (int k = 0; k < LENF; ++k) {
        float t = (float)k + 0.5f;
        w[k] = __expf(am1 * __logf(t) - t * inv_th);
        s += w[k];
    }
    float invs = 1.0f / s;
#pragma unroll
    for (int k = 0; k < LENF; ++k) uh[k * NB + b] = w[k] * invs;
}

__global__ __launch_bounds__(256) void conv_fb(const float* __restrict__ qs_ws,
                                               const float* __restrict__ qg_ws,
                                               const float* __restrict__ uh,
                                               float* __restrict__ out) {
    int b = blockIdx.x * 256 + threadIdx.x;
    int t = blockIdx.y;
    if (b >= NB) return;
    float ys = 0.0f, yg = 0.0f;
    int kmax = t < (LENF - 1) ? t : (LENF - 1);
    for (int k = 0; k <= kmax; ++k) {
        float w = uh[k * NB + b];
        ys = fmaf(qs_ws[(t - k) * NB + b], w, ys);
        yg = fmaf(qg_ws[(t - k) * NB + b], w, yg);
    }
    float* o = out + (t * NB + b) * 6;
    o[0] = ys + yg;
    o[1] = ys;
    o[2] = yg;
}

// ===========================================================================
extern "C" void kernel_launch(void* const* d_in, const int* in_sizes, int n_in,
                              void* d_out, int out_size, void* d_ws, size_t ws_size,
                              hipStream_t stream) {
    const float* x   = (const float*)d_in[0];   // (T,B,2) fp32
    const float* raw = (const float*)d_in[1];   // (B,34)  fp32
    float* out = (float*)d_out;                 // (T,B,6) fp32

    const size_t need = (size_t)T_STEPS * NB * sizeof(float2)
                      + (size_t)LENF * NB * sizeof(float);   // ~5.9 MB
    if (ws_size >= need) {
        float2* qsg = (float2*)d_ws;
        float*  uh  = (float*)(qsg + (size_t)T_STEPS * NB);
        uh_k      <<<dim3((NB + 255) / 256), dim3(256), 0, stream>>>(raw, uh);
        scan_fused<<<dim3(SGW / 64),         dim3(64),  0, stream>>>(x, raw, qsg, out);
        conv2     <<<dim3((NB + 255) / 256, T_STEPS), dim3(256), 0, stream>>>(qsg, uh, out);
    } else {
        float* qs = (float*)d_ws;
        float* qg = qs + (size_t)T_STEPS * NB;
        float* uh = qg + (size_t)T_STEPS * NB;
        float* dm = uh + (size_t)LENF * NB;
        uh_fb  <<<dim3((NB + 255) / 256),          dim3(256), 0, stream>>>(raw, uh);
        scan_fb<<<dim3(NB / 8),                    dim3(64),  0, stream>>>(x, raw, out, qs, qg, dm);
        conv_fb<<<dim3((NB + 255) / 256, T_STEPS), dim3(256), 0, stream>>>(qs, qg, uh, out);
    }
}

// Round 5
// 168.104 us; speedup vs baseline: 1.2868x; 1.2868x over previous
//
#include <hip/hip_runtime.h>
#include <math.h>

#define T_STEPS 730
#define NB      1000
#define LENF    15
#define NEARZ   1e-5f
#define CH      16             // steps per ring chunk
#define NCH     46             // 46*16 = 736 >= 730
#define SLOTS   4              // ring depth (double-double buffer)

// ===========================================================================
// 8-lane butterfly reduction (groups of 8 consecutive lanes = one basin).
// ===========================================================================
template <int CTRL>
__device__ __forceinline__ float dpp_mov(float x) {
    int xi = __builtin_bit_cast(int, x);
    int r  = __builtin_amdgcn_update_dpp(0, xi, CTRL, 0xF, 0xF, true);
    return __builtin_bit_cast(float, r);
}
__device__ __forceinline__ float sum8(float v) {
    v += dpp_mov<0xB1>(v);    // xor 1
    v += dpp_mov<0x4E>(v);    // xor 2
    v += dpp_mov<0x141>(v);   // half-mirror (completes 8-group)
    return v;
}

// ===========================================================================
// PRODUCER-CONSUMER FUSED PASS (R14).
// R4 post-mortem: 15 DPP + divergent stores INSIDE the serial loop cost
// ~470cy/step (590 vs 120).  R3's fix (separate kernel) cost a 46.7MB
// plane round-trip (~25us finalize).  This structure gets both: block =
// 3 waves on 3 SIMDs of one CU.
//   wave0: bare recurrence; per step 13 VALU + 1 ds_write_b64 into a
//          4-slot LDS ring.  NO global stores -> x prefetch vmcnt waits
//          are pure-load, prefetched a chunk ahead.
//   wave1/2: alternate 16-step chunks; read ring, recompute y via exp2
//          (exact inverse of producer's factor), 5x sum8 DPP reductions,
//          all global writes (ch3..5 + compact (qs,qg) plane).  Their
//          DPP hazards/exec-divergence run on OTHER SIMDs, fully off the
//          serial path, with t-level ILP.
// Sync: LDS flags + s_sleep polling (no s_barrier).  Producer guard keeps
// ring depth 4; consumers poll produced count.  Rates: producer ~50cy/step,
// consumer pair ~35cy/step effective -> producer-bound.
// ===========================================================================
#define PCH(CC, XC, XN)                                                        \
  {                                                                            \
    const int c = (CC);                                                        \
    if (c >= SLOTS) {                                                          \
        while (cv[c & 1] < c - 3) __builtin_amdgcn_s_sleep(2);                 \
    }                                                                          \
    float2* rw = &ring[c & 3][0][L];                                           \
    rw[0] = make_float2(S, G);               /* carry-in state */              \
    _Pragma("unroll")                                                          \
    for (int j = 0; j < CH; ++j) {           /* prefetch next chunk */         \
        int t = (c + 1) * CH + j;                                              \
        t = t < T_STEPS ? t : (T_STEPS - 1);                                   \
        XN[j] = xf[t * NB + b];                                                \
    }                                                                          \
    __builtin_amdgcn_sched_barrier(0);                                         \
    _Pragma("unroll")                                                          \
    for (int j = 0; j < CH; ++j) {                                             \
        float pcp = XC[j].x, pet = XC[j].y;                                    \
        float W     = pcp + S;                                                 \
        float term  = fmaf(W, inv2a, pb2a);                                    \
        float disc  = fmaf(term, term, -(W * boa));                            \
        float r     = __builtin_amdgcn_sqrtf(fmaxf(disc, NEARZ));              \
        float Y     = term - r;                                                \
        float e     = __builtin_amdgcn_exp2f(pet * nbl);                       \
        float Sn    = Y * e;                                                   \
        float avail = W - Y;                                                   \
        float Gn    = fmaf(pc, avail, G) * i1d;                                \
        S = Sn; G = Gn;                                                        \
        rw[(j + 1) * 64] = make_float2(Sn, Gn);                                \
    }                                                                          \
    __threadfence_block();                   /* drain ds_writes */             \
    if (L == 0) *pv = c + 1;                                                   \
  }

__global__ __launch_bounds__(192, 1) void scan_pc(const float* __restrict__ x,
                                                  const float* __restrict__ raw,
                                                  float2* __restrict__ qsg,
                                                  float* __restrict__ out) {
    __shared__ float2 ring[SLOTS][CH + 1][64];   // 34.8 KB
    __shared__ int produced;
    __shared__ int consumed[2];

    const int tid = threadIdx.x;
    const int wv  = tid >> 6;                // 0 = producer, 1/2 = consumers
    const int L   = tid & 63;
    const int b   = blockIdx.x * 8 + (L >> 3);
    const int m   = L & 7;

    if (tid == 0) { produced = 0; consumed[0] = 0; consumed[1] = 0; }
    __syncthreads();
    volatile int* pv = &produced;
    volatile int* cv = consumed;

    const float2* __restrict__ xf = (const float2*)x;
    const float* rp_ = raw + b * 34;         // (B,34)=[a(8),b(8),c(8),d(8),ra,rb]

    if (wv == 0) {
        // ---------------- producer: serial S/G recurrence ------------------
        float pa = rp_[0 * 8 + m] * 0.9f + 0.1f;
        float pb = rp_[1 * 8 + m] * 450.0f + 50.0f;
        float pc = rp_[2 * 8 + m];
        float pd = rp_[3 * 8 + m] * 0.89f + 0.01f;
        float inv2a = 1.0f / (2.0f * pa);
        float pb2a  = pb * inv2a;
        float boa   = pb / pa;
        float nbl   = -1.4426950408889634f / pb;  // exp(-pet/b)=exp2(pet*this)
        float i1d   = 1.0f / (1.0f + pd);
        float S = 50.0f, G = 10.0f;

        float2 Xa[CH], Xb[CH];
#pragma unroll
        for (int j = 0; j < CH; ++j) Xa[j] = xf[j * NB + b];   // chunk 0

        for (int c2 = 0; c2 < NCH; c2 += 2) {
            PCH(c2,     Xa, Xb)
            PCH(c2 + 1, Xb, Xa)
        }
    } else {
        // ---------------- consumers: reductions + global writes ------------
        float pbm = rp_[8 + m] * 450.0f + 50.0f;
        float e2s = 1.4426950408889634f / pbm;    // y = sn*exp2(pet*e2s)
        float omc = 1.0f - rp_[16 + m];
        float pd  = rp_[24 + m] * 0.89f + 0.01f;

        for (int c = wv - 1; c < NCH; c += 2) {
            // issue x loads for this chunk BEFORE polling (independent of ring)
            float2 xv[CH];
#pragma unroll
            for (int j = 0; j < CH; ++j) {
                int t = c * CH + j;
                t = t < T_STEPS ? t : (T_STEPS - 1);
                xv[j] = xf[t * NB + b];
            }
            while (*pv < c + 1) __builtin_amdgcn_s_sleep(2);
            __threadfence_block();
            const float2* rr = &ring[c & 3][0][L];
            float2 ebuf[CH + 1];
#pragma unroll
            for (int i = 0; i <= CH; ++i) ebuf[i] = rr[i * 64];
#pragma unroll
            for (int j = 0; j < CH; ++j) {
                const int t = c * CH + j;                // block-uniform
                if (t < T_STEPS) {
                    float sn = ebuf[j + 1].x, gn = ebuf[j + 1].y;
                    float sp = (t == 0) ? 50.0f : ebuf[j].x;
                    float y  = sn * __builtin_amdgcn_exp2f(xv[j].y * e2s);
                    float avail = (xv[j].x + sp) - y;
                    float qs = omc * avail;
                    float qg = pd * gn;
                    float qs_s = sum8(qs);
                    float qg_s = sum8(qg);
                    float y_s  = sum8(y);
                    float s_s  = sum8(sn);
                    float g_s  = sum8(gn);
                    if (m == 3) qsg[(size_t)t * NB + b] = make_float2(qs_s, qg_s);
                    float ov = (m == 0) ? (y_s - s_s) : ((m == 1) ? s_s : g_s);
                    if (m < 3) out[((size_t)t * NB + b) * 6 + 3 + m] = ov * 0.125f;
                }
            }
            __threadfence_block();           // reads/stores retired
            if (L == 0) cv[wv - 1] = c + 1;
        }
    }
}

// ===========================================================================
// UH weights, 0.125 ensemble mean folded (gammaln cancels under norm).
// ===========================================================================
__global__ __launch_bounds__(256) void uh_k(const float* __restrict__ raw,
                                            float* __restrict__ uh) {
    int b = blockIdx.x * 256 + threadIdx.x;
    if (b >= NB) return;
    float ra = raw[b * 34 + 32] * 2.9f;
    float rb = raw[b * 34 + 33] * 6.5f;
    float aa = fmaxf(ra, 0.0f) + 0.1f;
    float th = fmaxf(rb, 0.0f) + 0.5f;
    float inv_th = 1.0f / th;
    float am1 = aa - 1.0f;
    float w[LENF];
    float s = 0.0f;
#pragma unroll
    for (int k = 0; k < LENF; ++k) {
        float t = (float)k + 0.5f;
        w[k] = __expf(am1 * __logf(t) - t * inv_th);
        s += w[k];
    }
    float invs = 0.125f / s;       // UH normalization x ensemble mean
#pragma unroll
    for (int k = 0; k < LENF; ++k) uh[k * NB + b] = w[k] * invs;
}

// ===========================================================================
// 15-tap causal conv on the compact (qs,qg) plane -> out ch0..2.
// ===========================================================================
__global__ __launch_bounds__(256) void conv2(const float2* __restrict__ qsg,
                                             const float* __restrict__ uh,
                                             float* __restrict__ out) {
    int b = blockIdx.x * 256 + threadIdx.x;
    int t = blockIdx.y;
    if (b >= NB) return;
    float ys = 0.0f, yg = 0.0f;
    int kmax = t < (LENF - 1) ? t : (LENF - 1);
    for (int k = 0; k <= kmax; ++k) {
        float w  = uh[k * NB + b];
        float2 q = qsg[(size_t)(t - k) * NB + b];
        ys = fmaf(q.x, w, ys);
        yg = fmaf(q.y, w, yg);
    }
    float* o = out + ((size_t)t * NB + b) * 6;
    *(float2*)o = make_float2(ys + yg, ys);    // 8B-aligned (24|addr)
    o[2] = yg;
}

// ===========================================================================
// FALLBACK (ws too small): R8's proven path.
// ===========================================================================
#define STEPF(CURV)                                                            \
  {                                                                            \
    float pcp = (CURV).x, pet = (CURV).y;                                      \
    float W     = pcp + S;                                                     \
    float term  = fmaf(W, inv2a, pb2a);                                        \
    float disc  = fmaf(term, term, -(W * boa));                                \
    float r     = __builtin_amdgcn_sqrtf(fmaxf(disc, NEARZ));                  \
    float Y     = term - r;                                                    \
    float e     = __builtin_amdgcn_exp2f(pet * ninvbl2);                       \
    float Sn    = Y * e;                                                       \
    float AET   = Y - Sn;                                                      \
    float avail = W - Y;                                                       \
    float Qs    = omc * avail;                                                 \
    float Gn    = fmaf(pc, avail, G) * inv1pd;                                 \
    float Qg    = pd * Gn;                                                     \
    S = Sn; G = Gn;                                                            \
    float qs_s = sum8(Qs);                                                     \
    float qg_s = sum8(Qg);                                                     \
    float ae_s = sum8(AET);                                                    \
    float s_s  = sum8(Sn);                                                     \
    float g_s  = sum8(Gn);                                                     \
    float v = qs_s;                                                            \
    v = (m == 1) ? qg_s : v;                                                   \
    v = (m == 2) ? ae_s : v;                                                   \
    v = (m == 3) ? s_s  : v;                                                   \
    v = (m >= 4) ? g_s  : v;                                                   \
    *optr = v * 0.125f;                                                        \
    optr += incr;                                                              \
  }

__global__ __launch_bounds__(64, 1) void scan_fb(const float* __restrict__ x,
                                                 const float* __restrict__ raw,
                                                 float* __restrict__ out,
                                                 float* __restrict__ qs_ws,
                                                 float* __restrict__ qg_ws,
                                                 float* __restrict__ dummy) {
    const int L  = threadIdx.x;
    const int lb = L >> 3;
    const int m  = L & 7;
    const int b  = blockIdx.x * 8 + lb;

    const float* rp = raw + b * 34;
    float pa = rp[0 * 8 + m] * 0.9f + 0.1f;
    float pb = rp[1 * 8 + m] * 450.0f + 50.0f;
    float pc = rp[2 * 8 + m];
    float pd = rp[3 * 8 + m] * 0.89f + 0.01f;
    float inv2a   = 1.0f / (2.0f * pa);
    float pb2a    = pb * inv2a;
    float boa     = pb / pa;
    float ninvbl2 = -1.4426950408889634f / pb;
    float omc     = 1.0f - pc;
    float inv1pd  = 1.0f / (1.0f + pd);

    float* optr;
    long long incr;
    if      (m == 0) { optr = qs_ws + b;                      incr = NB;     }
    else if (m == 1) { optr = qg_ws + b;                      incr = NB;     }
    else if (m <= 4) { optr = out + (long long)b * 6 + m + 1; incr = NB * 6; }
    else             { optr = dummy + (blockIdx.x * 64 + L);  incr = 0;      }

    float S = 50.0f, G = 10.0f;
    const float2* __restrict__ xf = (const float2*)x;

    float2 A[10], B[10], C[10];
#pragma unroll
    for (int j = 0; j < 10; ++j) A[j] = xf[j * NB + b];
#pragma unroll
    for (int j = 0; j < 10; ++j) B[j] = xf[(10 + j) * NB + b];

    for (int cg = 0; cg < 24; ++cg) {
        const int c0 = 3 * cg;
#pragma unroll
        for (int j = 0; j < 10; ++j) C[j] = xf[((c0 + 2) * 10 + j) * NB + b];
        __builtin_amdgcn_sched_barrier(0);
#pragma unroll
        for (int j = 0; j < 10; ++j) STEPF(A[j]);
#pragma unroll
        for (int j = 0; j < 10; ++j) A[j] = xf[((c0 + 3) * 10 + j) * NB + b];
        __builtin_amdgcn_sched_barrier(0);
#pragma unroll
        for (int j = 0; j < 10; ++j) STEPF(B[j]);
#pragma unroll
        for (int j = 0; j < 10; ++j) {
            int t = (c0 + 4) * 10 + j;
            t = t < T_STEPS ? t : (T_STEPS - 1);
            B[j] = xf[t * NB + b];
        }
        __builtin_amdgcn_sched_barrier(0);
#pragma unroll
        for (int j = 0; j < 10; ++j) STEPF(C[j]);
    }
#pragma unroll
    for (int j = 0; j < 10; ++j) STEPF(A[j]);
}

__global__ __launch_bounds__(256) void uh_fb(const float* __restrict__ raw,
                                             float* __restrict__ uh) {
    int b = blockIdx.x * 256 + threadIdx.x;
    if (b >= NB) return;
    float ra = raw[b * 34 + 32] * 2.9f;
    float rb = raw[b * 34 + 33] * 6.5f;
    float aa = fmaxf(ra, 0.0f) + 0.1f;
    float th = fmaxf(rb, 0.0f) + 0.5f;
    float inv_th = 1.0f / th;
    float am1 = aa - 1.0f;
    float w[LENF];
    float s = 0.0f;
#pragma unroll
    for (int k = 0; k < LENF; ++k) {
        float t = (float)k + 0.5f;
        w[k] = __expf(am1 * __logf(t) - t * inv_th);
        s += w[k];
    }
    float invs = 1.0f / s;
#pragma unroll
    for (int k = 0; k < LENF; ++k) uh[k * NB + b] = w[k] * invs;
}

__global__ __launch_bounds__(256) void conv_fb(const float* __restrict__ qs_ws,
                                               const float* __restrict__ qg_ws,
                                               const float* __restrict__ uh,
                                               float* __restrict__ out) {
    int b = blockIdx.x * 256 + threadIdx.x;
    int t = blockIdx.y;
    if (b >= NB) return;
    float ys = 0.0f, yg = 0.0f;
    int kmax = t < (LENF - 1) ? t : (LENF - 1);
    for (int k = 0; k <= kmax; ++k) {
        float w = uh[k * NB + b];
        ys = fmaf(qs_ws[(t - k) * NB + b], w, ys);
        yg = fmaf(qg_ws[(t - k) * NB + b], w, yg);
    }
    float* o = out + (t * NB + b) * 6;
    o[0] = ys + yg;
    o[1] = ys;
    o[2] = yg;
}

// ===========================================================================
extern "C" void kernel_launch(void* const* d_in, const int* in_sizes, int n_in,
                              void* d_out, int out_size, void* d_ws, size_t ws_size,
                              hipStream_t stream) {
    const float* x   = (const float*)d_in[0];   // (T,B,2) fp32
    const float* raw = (const float*)d_in[1];   // (B,34)  fp32
    float* out = (float*)d_out;                 // (T,B,6) fp32

    const size_t need = (size_t)T_STEPS * NB * sizeof(float2)
                      + (size_t)LENF * NB * sizeof(float);   // ~5.9 MB
    if (ws_size >= need) {
        float2* qsg = (float2*)d_ws;
        float*  uh  = (float*)(qsg + (size_t)T_STEPS * NB);
        uh_k   <<<dim3((NB + 255) / 256), dim3(256), 0, stream>>>(raw, uh);
        scan_pc<<<dim3(NB / 8),           dim3(192), 0, stream>>>(x, raw, qsg, out);
        conv2  <<<dim3((NB + 255) / 256, T_STEPS), dim3(256), 0, stream>>>(qsg, uh, out);
    } else {
        float* qs = (float*)d_ws;
        float* qg = qs + (size_t)T_STEPS * NB;
        float* uh = qg + (size_t)T_STEPS * NB;
        float* dm = uh + (size_t)LENF * NB;
        uh_fb  <<<dim3((NB + 255) / 256),          dim3(256), 0, stream>>>(raw, uh);
        scan_fb<<<dim3(NB / 8),                    dim3(64),  0, stream>>>(x, raw, out, qs, qg, dm);
        conv_fb<<<dim3((NB + 255) / 256, T_STEPS), dim3(256), 0, stream>>>(qs, qg, uh, out);
    }
}

// Round 6
// 125.907 us; speedup vs baseline: 1.7180x; 1.3351x over previous
//
#include <hip/hip_runtime.h>
#include <math.h>

#define T_STEPS 730
#define NB      1000
#define LENF    15
#define NEARZ   1e-5f
#define SGW     8000           // 1000 basins x 8 members (lanes)
#define TT      64             // finalize tile rows == checkpoint stride
#define BBLK    32             // finalize: basins per block
#define NPAIR   365            // 730/2 S-pairs per lane
#define NCHK    11             // G checkpoints at t = 64k-15, k=1..11

// ===========================================================================
// R6 (post R4/R5 structural failures -> consolidate on R3 split structure):
//  * scan stores ONLY S, packed in (S_2p,S_2p+1) float2 pairs -> 23.4MB plane,
//    365 store insts (was 730 dwordx2 / 46.7MB).
//  * G is a LINEAR IIR -> finalize integrates it exactly in-register during
//    its serial row walk, seeded from 11 G-checkpoints (t=64k-15) the scan
//    writes (0.35MB).  Finalize reads drop 60MB -> ~29MB.
//  * finalize TT=64, 3-phase statically-indexed pair pipeline, conv inline.
// ===========================================================================

// 8-lane butterfly reduction (8 consecutive lanes = one basin).
template <int CTRL>
__device__ __forceinline__ float dpp_mov(float x) {
    int xi = __builtin_bit_cast(int, x);
    int r  = __builtin_amdgcn_update_dpp(0, xi, CTRL, 0xF, 0xF, true);
    return __builtin_bit_cast(float, r);
}
__device__ __forceinline__ float sum8(float v) {
    v += dpp_mov<0xB1>(v);    // xor 1
    v += dpp_mov<0x4E>(v);    // xor 2
    v += dpp_mov<0x141>(v);   // half-mirror (completes 8-group)
    return v;
}

// ===========================================================================
// PASS A: serial S/G recurrence; forcing staged in LDS (R3-proven: loop has
// no global loads -> no vmcnt waits couple to the store queue).
// Per step: 13 VALU + 0.5 store + 1 ds_read (amortized) + ~2 SALU.
// ===========================================================================
#define STEPA(CURV, TB, J)                                                     \
  {                                                                            \
    float pcp = (CURV).x, pet = (CURV).y;                                      \
    float W     = pcp + S;                                                     \
    float term  = fmaf(W, inv2a, pb2a);                                        \
    float disc  = fmaf(term, term, -(W * boa));                                \
    float r     = __builtin_amdgcn_sqrtf(fmaxf(disc, NEARZ));                  \
    float Y     = term - r;                                                    \
    float e     = __builtin_amdgcn_exp2f(pet * nbl);                           \
    float Sn    = Y * e;                                                       \
    float avail = W - Y;                                                       \
    float Gn    = fmaf(pc, avail, G) * i1d;                                    \
    S = Sn; G = Gn;                                                            \
    if (((J) & 1) == 0) Skeep = Sn;                                            \
    else { *ps2 = make_float2(Skeep, Sn); ps2 += SGW; }                        \
    if ((TB) + (J) == nextchk) { *gc = Gn; gc += SGW; nextchk += TT; }         \
  }

// LDS prefetch: rows up to 735 valid (duplicates of 729) -> no clamp.
#define PREFETCH(BUF, CI)                                                      \
  _Pragma("unroll")                                                            \
  for (int j = 0; j < 8; ++j) {                                                \
      BUF[j] = xs[((CI) * 8 + j) * 8 + bl];                                    \
  }                                                                            \
  __builtin_amdgcn_sched_barrier(0);

__global__ __launch_bounds__(64, 1) void scan_state(const float* __restrict__ x,
                                                    const float* __restrict__ raw,
                                                    float2* __restrict__ sp,
                                                    float* __restrict__ gchk) {
    __shared__ float4 xs4[2944];               // 736 rows x 8 basins x float2
    const float2* xs = (const float2*)xs4;

    const int L   = threadIdx.x;
    const int gid = blockIdx.x * 64 + L;       // 0..7999 (grid=125)
    const int b   = gid >> 3;
    const int m   = gid & 7;
    const int bl  = L >> 3;                    // basin-local 0..7

    // ---- one-time cooperative x -> LDS stage ------------------------------
    {
        float4 tmp[46];
#pragma unroll
        for (int ch = 0; ch < 46; ++ch) {
            int idx = ch * 64 + L;             // 0..2943
            int row = idx >> 2;                // t row 0..735
            row = row < T_STEPS ? row : (T_STEPS - 1);
            tmp[ch] = *(const float4*)((const char*)x + (size_t)row * (NB * 8)
                                       + (size_t)(blockIdx.x * 64)
                                       + (size_t)(idx & 3) * 16);
        }
#pragma unroll
        for (int ch = 0; ch < 46; ++ch) xs4[ch * 64 + L] = tmp[ch];
    }
    __syncthreads();

    // raw layout (B,34) = [a(8), b(8), c(8), d(8), ra, rb]
    const float* rp = raw + b * 34;
    float pa = rp[0 * 8 + m] * 0.9f + 0.1f;
    float pb = rp[1 * 8 + m] * 450.0f + 50.0f;
    float pc = rp[2 * 8 + m];
    float pd = rp[3 * 8 + m] * 0.89f + 0.01f;

    float inv2a = 1.0f / (2.0f * pa);
    float pb2a  = pb * inv2a;
    float boa   = pb / pa;
    float nbl   = -1.4426950408889634f / pb;   // exp(-pet/b)=exp2(pet*this)
    float i1d   = 1.0f / (1.0f + pd);

    float S = 50.0f, G = 10.0f, Skeep = 0.0f;
    float2* ps2 = sp + gid;                    // advances SGW float2 per pair
    float*  gc  = gchk + gid;                  // advances SGW per checkpoint
    int nextchk = TT - 15;                     // 49, 113, ..., 689

    float2 A[8], Bb[8], Cc[8];
    PREFETCH(A, 0)
    PREFETCH(Bb, 1)

    // 15 groups x 48 steps (6 chunks of 8) = 720 steps, + 10-step tail.
    for (int g = 0; g < 15; ++g) {
        const int c0 = 6 * g;
        const int t0 = 48 * g;
        PREFETCH(Cc, c0 + 2)
#pragma unroll
        for (int j = 0; j < 8; ++j) STEPA(A[j],  t0,      j)
        PREFETCH(A, c0 + 3)
#pragma unroll
        for (int j = 0; j < 8; ++j) STEPA(Bb[j], t0 + 8,  j)
        PREFETCH(Bb, c0 + 4)
#pragma unroll
        for (int j = 0; j < 8; ++j) STEPA(Cc[j], t0 + 16, j)
        PREFETCH(Cc, c0 + 5)
#pragma unroll
        for (int j = 0; j < 8; ++j) STEPA(A[j],  t0 + 24, j)
        PREFETCH(A, c0 + 6)
#pragma unroll
        for (int j = 0; j < 8; ++j) STEPA(Bb[j], t0 + 32, j)
        PREFETCH(Bb, c0 + 7)
#pragma unroll
        for (int j = 0; j < 8; ++j) STEPA(Cc[j], t0 + 40, j)
    }
    // tail: A = rows 720..727, Bb[0]=728, Bb[1]=729 (closes the last pair)
#pragma unroll
    for (int j = 0; j < 8; ++j) STEPA(A[j], 720, j)
    STEPA(Bb[0], 728, 0)
    STEPA(Bb[1], 728, 1)
}

// ===========================================================================
// PASS B: t-parallel finalize on the paired S-plane.
// Block = 256 thr = 32 basins x 8 members; grid (12, 32).
// 3-phase statically-indexed pair pipeline over 39 pairs (78 rows incl 14
// halo); S[t-1] carried in-register (seeded from pair (tbase-16)/2 .y);
// G integrated exactly in-register from the scan's checkpoint; 8-lane DPP
// reduce; qs/qg staged in LDS; 15-tap gamma-UH conv inline.
// ===========================================================================
#define ROW(SN, XV, TTE, RE)                                                   \
  {                                                                            \
    const int tt = (TTE); const int r = (RE);                                  \
    const bool tval = (tt >= 0) && (tt < T_STEPS);                             \
    float qs = 0.f, qg = 0.f, aet = 0.f, sX = 0.f, gX = 0.f;                   \
    if (tval) {                                                                \
      float sn  = (SN);                                                        \
      float spv = (tt == 0) ? 50.0f : Sprev;                                   \
      float y   = sn * __builtin_amdgcn_exp2f((XV).y * e2s);                   \
      float avail = ((XV).x + spv) - y;                                        \
      G = fmaf(pc, avail, G) * i1d;                                            \
      qs = omc * avail; qg = pd * G; aet = y - sn; sX = sn; gX = G;            \
      Sprev = sn;                                                              \
    }                                                                          \
    qs = sum8(qs); qg = sum8(qg);                                              \
    if (m == 0) { qsh[r][lb] = qs; qgh[r][lb] = qg; }                          \
    if (r >= 14 && tval) {                                                     \
      float a_s = sum8(aet), s_s = sum8(sX), g_s = sum8(gX);                   \
      if (bval && m < 3) {                                                     \
        float v = (m == 0) ? a_s : ((m == 1) ? s_s : g_s);                     \
        out[((size_t)tt * NB + b) * 6 + 3 + m] = v * 0.125f;                   \
      }                                                                        \
    }                                                                          \
  }

#define PAIRSTEP(PH)                                                           \
  {                                                                            \
    const int pidx = g2 * 3 + (PH);                                            \
    const int tt0  = tbase - 14 + 2 * pidx;                                    \
    float2 sv  = sb[PH];                                                       \
    float2 xv0 = x0b[PH];                                                      \
    float2 xv1 = x1b[PH];                                                      \
    { int tp = tt0 + 6; tp = tp < 0 ? 0 : (tp > 728 ? 728 : tp);               \
      sb[PH]  = sp[(size_t)(tp >> 1) * SGW + lane];                            \
      x0b[PH] = xf[tp * NB + bc];                                              \
      x1b[PH] = xf[(tp + 1) * NB + bc]; }                                      \
    ROW(sv.x, xv0, tt0,     2 * pidx)                                          \
    ROW(sv.y, xv1, tt0 + 1, 2 * pidx + 1)                                      \
  }

__global__ __launch_bounds__(256) void finalize(const float* __restrict__ x,
                                                const float* __restrict__ raw,
                                                const float2* __restrict__ sp,
                                                const float* __restrict__ gchk,
                                                float* __restrict__ out) {
    __shared__ float qsh[TT + 14][BBLK + 1];
    __shared__ float qgh[TT + 14][BBLK + 1];

    const int tid   = threadIdx.x;
    const int lb    = tid >> 3;          // local basin 0..31
    const int m     = tid & 7;
    const int tbase = blockIdx.x * TT;
    const int b0    = blockIdx.y * BBLK;
    const int b     = b0 + lb;
    const bool bval = b < NB;
    const int bc    = bval ? b : (NB - 1);      // clamped for loads
    const int lane  = bc * 8 + m;               // 0..7999

    const float* rp = raw + bc * 34;
    float pbm = rp[8 + m] * 450.0f + 50.0f;
    float e2s = 1.4426950408889634f / pbm;      // y = sn * exp2(pet * e2s)
    float pc  = rp[16 + m];
    float omc = 1.0f - pc;
    float pd  = rp[24 + m] * 0.89f + 0.01f;
    float i1d = 1.0f / (1.0f + pd);

    const float2* __restrict__ xf = (const float2*)x;

    // seeds: G after step tbase-15 (checkpoint), S at tbase-15 (pair .y)
    float G     = (blockIdx.x == 0) ? 10.0f
                  : gchk[(size_t)(blockIdx.x - 1) * SGW + lane];
    float Sprev = 50.0f;
    if (tbase > 0) Sprev = sp[(size_t)((tbase - 16) >> 1) * SGW + lane].y;

    // ---- 3-deep pair pipeline: 39 pairs = 13 groups x 3 ------------------
    float2 sb[3], x0b[3], x1b[3];
#pragma unroll
    for (int d = 0; d < 3; ++d) {
        int tp = tbase - 14 + 2 * d;
        tp = tp < 0 ? 0 : (tp > 728 ? 728 : tp);
        sb[d]  = sp[(size_t)(tp >> 1) * SGW + lane];
        x0b[d] = xf[tp * NB + bc];
        x1b[d] = xf[(tp + 1) * NB + bc];
    }

    for (int g2 = 0; g2 < 13; ++g2) {
        PAIRSTEP(0)
        PAIRSTEP(1)
        PAIRSTEP(2)
    }
    __syncthreads();

    // ---- conv phase: threads = (t-slot 0..7) x (basin 0..31) -------------
    const int bl2 = tid & 31;
    const int tl0 = tid >> 5;                   // 0..7
    const int b2  = b0 + bl2;
    if (b2 >= NB) return;

    const float* rp2 = raw + b2 * 34;
    float ra = rp2[32] * 2.9f;
    float rb = rp2[33] * 6.5f;
    float aa = fmaxf(ra, 0.0f) + 0.1f;
    float th = fmaxf(rb, 0.0f) + 0.5f;
    float inv_th = 1.0f / th;
    float am1 = aa - 1.0f;
    float w[LENF];
    float sw = 0.0f;
#pragma unroll
    for (int k = 0; k < LENF; ++k) {
        float tk = (float)k + 0.5f;
        w[k] = __expf(am1 * __logf(tk) - tk * inv_th);
        sw += w[k];
    }
    float invs = 0.125f / sw;      // UH normalization x ensemble mean
#pragma unroll
    for (int k = 0; k < LENF; ++k) w[k] *= invs;

#pragma unroll
    for (int it = 0; it < 8; ++it) {
        int tl = tl0 + it * 8;                  // 0..63
        int t  = tbase + tl;
        if (t < T_STEPS) {
            float ys = 0.0f, yg = 0.0f;
#pragma unroll
            for (int k = 0; k < LENF; ++k) {
                ys = fmaf(qsh[tl + 14 - k][bl2], w[k], ys);
                yg = fmaf(qgh[tl + 14 - k][bl2], w[k], yg);
            }
            float* o = out + ((size_t)t * NB + b2) * 6;
            o[0] = ys + yg;
            o[1] = ys;
            o[2] = yg;
        }
    }
}

// ===========================================================================
// FALLBACK (ws too small): R8's proven path.
// ===========================================================================
#define STEPF(CURV)                                                            \
  {                                                                            \
    float pcp = (CURV).x, pet = (CURV).y;                                      \
    float W     = pcp + S;                                                     \
    float term  = fmaf(W, inv2a, pb2a);                                        \
    float disc  = fmaf(term, term, -(W * boa));                                \
    float r     = __builtin_amdgcn_sqrtf(fmaxf(disc, NEARZ));                  \
    float Y     = term - r;                                                    \
    float e     = __builtin_amdgcn_exp2f(pet * ninvbl2);                       \
    float Sn    = Y * e;                                                       \
    float AET   = Y - Sn;                                                      \
    float avail = W - Y;                                                       \
    float Qs    = omc * avail;                                                 \
    float Gn    = fmaf(pc, avail, G) * inv1pd;                                 \
    float Qg    = pd * Gn;                                                     \
    S = Sn; G = Gn;                                                            \
    float qs_s = sum8(Qs);                                                     \
    float qg_s = sum8(Qg);                                                     \
    float ae_s = sum8(AET);                                                    \
    float s_s  = sum8(Sn);                                                     \
    float g_s  = sum8(Gn);                                                     \
    float v = qs_s;                                                            \
    v = (m == 1) ? qg_s : v;                                                   \
    v = (m == 2) ? ae_s : v;                                                   \
    v = (m == 3) ? s_s  : v;                                                   \
    v = (m >= 4) ? g_s  : v;                                                   \
    *optr = v * 0.125f;                                                        \
    optr += incr;                                                              \
  }

__global__ __launch_bounds__(64, 1) void scan_fb(const float* __restrict__ x,
                                                 const float* __restrict__ raw,
                                                 float* __restrict__ out,
                                                 float* __restrict__ qs_ws,
                                                 float* __restrict__ qg_ws,
                                                 float* __restrict__ dummy) {
    const int L  = threadIdx.x;
    const int lb = L >> 3;
    const int m  = L & 7;
    const int b  = blockIdx.x * 8 + lb;

    const float* rp = raw + b * 34;
    float pa = rp[0 * 8 + m] * 0.9f + 0.1f;
    float pb = rp[1 * 8 + m] * 450.0f + 50.0f;
    float pc = rp[2 * 8 + m];
    float pd = rp[3 * 8 + m] * 0.89f + 0.01f;
    float inv2a   = 1.0f / (2.0f * pa);
    float pb2a    = pb * inv2a;
    float boa     = pb / pa;
    float ninvbl2 = -1.4426950408889634f / pb;
    float omc     = 1.0f - pc;
    float inv1pd  = 1.0f / (1.0f + pd);

    float* optr;
    long long incr;
    if      (m == 0) { optr = qs_ws + b;                      incr = NB;     }
    else if (m == 1) { optr = qg_ws + b;                      incr = NB;     }
    else if (m <= 4) { optr = out + (long long)b * 6 + m + 1; incr = NB * 6; }
    else             { optr = dummy + (blockIdx.x * 64 + L);  incr = 0;      }

    float S = 50.0f, G = 10.0f;
    const float2* __restrict__ xf = (const float2*)x;

    float2 A[10], B[10], C[10];
#pragma unroll
    for (int j = 0; j < 10; ++j) A[j] = xf[j * NB + b];
#pragma unroll
    for (int j = 0; j < 10; ++j) B[j] = xf[(10 + j) * NB + b];

    for (int cg = 0; cg < 24; ++cg) {
        const int c0 = 3 * cg;
#pragma unroll
        for (int j = 0; j < 10; ++j) C[j] = xf[((c0 + 2) * 10 + j) * NB + b];
        __builtin_amdgcn_sched_barrier(0);
#pragma unroll
        for (int j = 0; j < 10; ++j) STEPF(A[j]);
#pragma unroll
        for (int j = 0; j < 10; ++j) A[j] = xf[((c0 + 3) * 10 + j) * NB + b];
        __builtin_amdgcn_sched_barrier(0);
#pragma unroll
        for (int j = 0; j < 10; ++j) STEPF(B[j]);
#pragma unroll
        for (int j = 0; j < 10; ++j) {
            int t = (c0 + 4) * 10 + j;
            t = t < T_STEPS ? t : (T_STEPS - 1);
            B[j] = xf[t * NB + b];
        }
        __builtin_amdgcn_sched_barrier(0);
#pragma unroll
        for (int j = 0; j < 10; ++j) STEPF(C[j]);
    }
#pragma unroll
    for (int j = 0; j < 10; ++j) STEPF(A[j]);
}

__global__ __launch_bounds__(256) void uh_fb(const float* __restrict__ raw,
                                             float* __restrict__ uh) {
    int b = blockIdx.x * 256 + threadIdx.x;
    if (b >= NB) return;
    float ra = raw[b * 34 + 32] * 2.9f;
    float rb = raw[b * 34 + 33] * 6.5f;
    float aa = fmaxf(ra, 0.0f) + 0.1f;
    float th = fmaxf(rb, 0.0f) + 0.5f;
    float inv_th = 1.0f / th;
    float am1 = aa - 1.0f;
    float w[LENF];
    float s = 0.0f;
#pragma unroll
    for (int k = 0; k < LENF; ++k) {
        float t = (float)k + 0.5f;
        w[k] = __expf(am1 * __logf(t) - t * inv_th);
        s += w[k];
    }
    float invs = 1.0f / s;
#pragma unroll
    for (int k = 0; k < LENF; ++k) uh[k * NB + b] = w[k] * invs;
}

__global__ __launch_bounds__(256) void conv_fb(const float* __restrict__ qs_ws,
                                               const float* __restrict__ qg_ws,
                                               const float* __restrict__ uh,
                                               float* __restrict__ out) {
    int b = blockIdx.x * 256 + threadIdx.x;
    int t = blockIdx.y;
    if (b >= NB) return;
    float ys = 0.0f, yg = 0.0f;
    int kmax = t < (LENF - 1) ? t : (LENF - 1);
    for (int k = 0; k <= kmax; ++k) {
        float w = uh[k * NB + b];
        ys = fmaf(qs_ws[(t - k) * NB + b], w, ys);
        yg = fmaf(qg_ws[(t - k) * NB + b], w, yg);
    }
    float* o = out + (t * NB + b) * 6;
    o[0] = ys + yg;
    o[1] = ys;
    o[2] = yg;
}

// ===========================================================================
extern "C" void kernel_launch(void* const* d_in, const int* in_sizes, int n_in,
                              void* d_out, int out_size, void* d_ws, size_t ws_size,
                              hipStream_t stream) {
    const float* x   = (const float*)d_in[0];   // (T,B,2) fp32
    const float* raw = (const float*)d_in[1];   // (B,34)  fp32
    float* out = (float*)d_out;                 // (T,B,6) fp32

    const size_t need = (size_t)NPAIR * SGW * sizeof(float2)
                      + (size_t)NCHK * SGW * sizeof(float);   // ~23.7 MB
    if (ws_size >= need) {
        float2* sp   = (float2*)d_ws;
        float*  gchk = (float*)(sp + (size_t)NPAIR * SGW);
        scan_state<<<dim3(SGW / 64), dim3(64),  0, stream>>>(x, raw, sp, gchk);
        finalize  <<<dim3((T_STEPS + TT - 1) / TT, (NB + BBLK - 1) / BBLK),
                     dim3(256), 0, stream>>>(x, raw, sp, gchk, out);
    } else {
        float* qs = (float*)d_ws;
        float* qg = qs + (size_t)T_STEPS * NB;
        float* uh = qg + (size_t)T_STEPS * NB;
        float* dm = uh + (size_t)LENF * NB;
        uh_fb  <<<dim3((NB + 255) / 256),          dim3(256), 0, stream>>>(raw, uh);
        scan_fb<<<dim3(NB / 8),                    dim3(64),  0, stream>>>(x, raw, out, qs, qg, dm);
        conv_fb<<<dim3((NB + 255) / 256, T_STEPS), dim3(256), 0, stream>>>(qs, qg, uh, out);
    }
}